// Round 3
// baseline (361.924 us; speedup 1.0000x reference)
//
#include <hip/hip_runtime.h>

typedef __bf16 bf16x8 __attribute__((ext_vector_type(8)));
typedef unsigned short u16x8 __attribute__((ext_vector_type(8)));
typedef float f32x4 __attribute__((ext_vector_type(4)));

__device__ __forceinline__ unsigned short f2bf(float f) {
    unsigned u = __builtin_bit_cast(unsigned, f);
    u += 0x7FFFu + ((u >> 16) & 1u);            // RNE
    return (unsigned short)(u >> 16);
}
__device__ __forceinline__ float bflo(unsigned w) {   // low bf16 half -> f32
    return __builtin_bit_cast(float, w << 16);
}
__device__ __forceinline__ float bfhi(unsigned w) {   // high bf16 half -> f32
    return __builtin_bit_cast(float, w & 0xFFFF0000u);
}

// ---------------------------------------------------------------------------
// Pre-kernel: w2 (128,3,256) fp32 -> w2t[i][kappa] bf16, kappa = k*128 + j2
// ---------------------------------------------------------------------------
__global__ void prep_w2(const float* __restrict__ w2, unsigned short* __restrict__ w2t) {
    int idx = blockIdx.x * 256 + threadIdx.x;
    if (idx < 128 * 3 * 256) {
        int i  = idx % 256;
        int jk = idx / 256;                     // j2*3 + k
        int j2 = jk / 3, k = jk % 3;
        w2t[i * 384 + k * 128 + j2] = f2bf(w2[idx]);
    }
}

// load 14 consecutive floats whose base is 8B-aligned; odd => base%4==2 (floats)
__device__ __forceinline__ void load14(const float* __restrict__ p, bool odd, float v[14]) {
    if (odd) {
        const float2 a  = *(const float2*)(p);
        const float4 q0 = *(const float4*)(p + 2);
        const float4 q1 = *(const float4*)(p + 6);
        const float4 q2 = *(const float4*)(p + 10);
        v[0]=a.x;  v[1]=a.y;
        v[2]=q0.x; v[3]=q0.y; v[4]=q0.z;  v[5]=q0.w;
        v[6]=q1.x; v[7]=q1.y; v[8]=q1.z;  v[9]=q1.w;
        v[10]=q2.x; v[11]=q2.y; v[12]=q2.z; v[13]=q2.w;
    } else {
        const float4 q0 = *(const float4*)(p);
        const float4 q1 = *(const float4*)(p + 4);
        const float4 q2 = *(const float4*)(p + 8);
        const float2 a  = *(const float2*)(p + 12);
        v[0]=q0.x; v[1]=q0.y; v[2]=q0.z;  v[3]=q0.w;
        v[4]=q1.x; v[5]=q1.y; v[6]=q1.z;  v[7]=q1.w;
        v[8]=q2.x; v[9]=q2.y; v[10]=q2.z; v[11]=q2.w;
        v[12]=a.x; v[13]=a.y;
    }
}

// ---------------------------------------------------------------------------
// Fused kernel, v2b: 2 blocks per m (l-split with 1-l halo).
//   half=0: stages l in [0..6,13] (li order), outputs cdx 1..7
//   half=1: stages l in [6..13],   outputs cdx 8..13,0
//   112 local rows = exactly 7 MFMA row-tiles; LDS 46.6 KB -> 3 blocks/CU.
//   C-buffer TRANSPOSED [row][col] stride-18 -> conflict-free u32 epilogue.
//   v2b fix: explicit waitcnt+memory fences around the cb write->read phase
//   (TBAA saw u16 stores vs u32 loads as non-aliasing -> reordered -> NaN).
// ---------------------------------------------------------------------------
__global__ __launch_bounds__(256, 3) void fused_conv_outer2(
    const float* __restrict__ x, const float* __restrict__ w1,
    const unsigned short* __restrict__ w2t, float* __restrict__ out)
{
    __shared__ alignas(16) unsigned short xlds[112 * 136];   // 30,464 B
    __shared__ alignas(16) unsigned short cb[4 * 112 * 18];  // 16,128 B

    const int m    = blockIdx.x >> 1;
    const int half = blockIdx.x & 1;
    const int tid  = threadIdx.x;
    const int wave = tid >> 6;
    const int lane = tid & 63;
    const int c16  = lane & 15;      // MFMA A-row / D-col index
    const int kgrp = lane >> 4;      // 0..3

    // ---------------- stage this block's 8 l-slices -> xlds (bf16) ----------------
    {
        const float* xm = x + (size_t)m * 25088;      // x4[m][j2][l][h], j2 stride 196
        const int j2a = 2 * lane;                     // lane owns j2a, j2a+1
#pragma unroll
        for (int t = 0; t < 2; ++t) {
            const int li = wave * 2 + t;              // local l index 0..7
            const int gl = half ? (6 + li) : (li < 7 ? li : 13);   // global l
            float va[14], vb[14];
            const float* b0 = xm + (size_t)j2a * 196 + gl * 14;
            load14(b0,       (gl & 1) != 0, va);
            load14(b0 + 196, (gl & 1) != 0, vb);
            unsigned short* dst = &xlds[(li * 14) * 136 + j2a];
#pragma unroll
            for (int h = 0; h < 14; ++h) {
                unsigned pk = (unsigned)f2bf(va[h]) | ((unsigned)f2bf(vb[h]) << 16);
                *(unsigned*)&dst[h * 136] = pk;       // banks = lane%32 : conflict-free
            }
        }
    }
    __syncthreads();

    unsigned short* cbw = &cb[wave * (112 * 18)];
    float* outm = out + (size_t)m * 50176;

#pragma unroll 1
    for (int nt = 0; nt < 4; ++nt) {
        const int ntile   = wave * 4 + nt;
        const int colbase = ntile * 16;

        // ---- B fragments for this 16-col tile, all 12 k-steps ----
        bf16x8 Bf[12];
        {
            const unsigned short* bp = w2t + (size_t)(colbase + c16) * 384 + kgrp * 8;
#pragma unroll
            for (int k = 0; k < 12; ++k)
                Bf[k] = __builtin_bit_cast(bf16x8, *(const u16x8*)(bp + k * 32));
        }

#pragma unroll 1
        for (int mt = 0; mt < 7; ++mt) {
            const int r0 = mt * 16 + c16;             // local GEMM row, always < 112
            const int nn = r0 % 14;                   // spatial n of this row

            bf16x8 Af[12];
#pragma unroll
            for (int k = 0; k < 12; ++k) {
                const int tap = k >> 2;               // kappa/128
                const int h   = nn + tap - 1;         // window position within l
                if ((unsigned)h < 14u) {
                    Af[k] = __builtin_bit_cast(bf16x8,
                        *(const u16x8*)&xlds[(r0 + tap - 1) * 136 + (k & 3) * 32 + kgrp * 8]);
                } else {
                    Af[k] = __builtin_bit_cast(bf16x8, (u16x8)(unsigned short)0);
                }
            }

            f32x4 acc = {0.f, 0.f, 0.f, 0.f};
#pragma unroll
            for (int k = 0; k < 12; ++k)
                acc = __builtin_amdgcn_mfma_f32_16x16x32_bf16(Af[k], Bf[k], acc, 0, 0, 0);

            // D layout: col = lane&15, row = kgrp*4 + reg.  Transposed store [row][col].
            const int rrb = mt * 16 + kgrp * 4;
#pragma unroll
            for (int j = 0; j < 4; ++j)
                cbw[(rrb + j) * 18 + c16] = f2bf(acc[j]);
        }

        // Fence: drain this wave's cb ds_writes and forbid the compiler from
        // hoisting the (TBAA-"non-aliasing") u32 epilogue reads above them.
        asm volatile("s_waitcnt lgkmcnt(0)" ::: "memory");

        // ---------------- fused epilogue: 16 channels, 7 cdx x 14 n = 98 rows --------
        // out[i, cdx, n] = w1[i,0]*t4[l=cdx-1][n][i] + w1[i,1]*t4[l=cdx-2][n][i]
        float4 wv[8];
#pragma unroll
        for (int cp = 0; cp < 8; ++cp)
            wv[cp] = *(const float4*)(w1 + (colbase + 2 * cp) * 2);   // wave-uniform

        float* op = outm + (size_t)colbase * 196;
#pragma unroll
        for (int it = 0; it < 2; ++it) {
            const int e   = it * 64 + lane;
            const bool ok = (e < 98);
            const int ec  = ok ? e : 97;
            const int ci  = ec / 14;                  // local output-row index 0..6
            const int n2  = ec - ci * 14;
            int li1, li2, o;
            if (half) { li1 = ci + 1; li2 = ci;            o = e + 112 - (ci == 6 ? 196 : 0); }
            else      { li1 = ci;     li2 = (ci + 7) & 7;  o = e + 14; }
            const int r1o = (li1 * 14 + n2) * 18;
            const int r2o = (li2 * 14 + n2) * 18;
#pragma unroll
            for (int cp = 0; cp < 8; ++cp) {
                const unsigned A = *(const unsigned*)&cbw[r1o + 2 * cp];  // cols 2cp,2cp+1
                const unsigned B = *(const unsigned*)&cbw[r2o + 2 * cp];
                if (ok) {
                    op[(2 * cp) * 196 + o]     = wv[cp].x * bflo(A) + wv[cp].y * bflo(B);
                    op[(2 * cp + 1) * 196 + o] = wv[cp].z * bfhi(A) + wv[cp].w * bfhi(B);
                }
            }
        }

        // Compiler fence for the WAR hazard: next nt's cb ds_writes must not be
        // hoisted above this epilogue's ds_reads (HW executes same-wave DS in order).
        asm volatile("" ::: "memory");
    }
}

extern "C" void kernel_launch(void* const* d_in, const int* in_sizes, int n_in,
                              void* d_out, int out_size, void* d_ws, size_t ws_size,
                              hipStream_t stream) {
    const float* x  = (const float*)d_in[0];   // (1024,1792,14) fp32
    const float* w1 = (const float*)d_in[1];   // (256,2) fp32
    const float* w2 = (const float*)d_in[2];   // (128,3,256) fp32
    float* out = (float*)d_out;                // (1024,256,14,14) fp32
    unsigned short* w2t = (unsigned short*)d_ws;  // 256*384 bf16 = 196,608 B

    prep_w2<<<384, 256, 0, stream>>>(w2, w2t);
    fused_conv_outer2<<<2048, 256, 0, stream>>>(x, w1, w2t, out);
}